// Round 6
// baseline (1423.400 us; speedup 1.0000x reference)
//
#include <hip/hip_runtime.h>

#define BB 512
#define LL 1024
#define DD 16
#define HH 64
#define CH 16    // timesteps per chunk

typedef _Float16 half2_t __attribute__((ext_vector_type(2)));

__device__ __forceinline__ half2_t h2(unsigned u) {
    return __builtin_bit_cast(half2_t, u);
}
__device__ __forceinline__ unsigned pk2_(float a, float b) {
    unsigned ha = (unsigned)__builtin_bit_cast(unsigned short, (_Float16)a);
    unsigned hb = (unsigned)__builtin_bit_cast(unsigned short, (_Float16)b);
    return ha | (hb << 16);
}
__device__ __forceinline__ float flo_(float a) {   // a - f16(a)
    return a - (float)((_Float16)a);
}
__device__ __forceinline__ float sigmoidf_(float x) {
    return __builtin_amdgcn_rcpf(1.0f + __expf(-x));
}
__device__ __forceinline__ float tanhf_(float x) {
    x = fminf(fmaxf(x, -15.0f), 15.0f);
    float e = __expf(2.0f * x);
    return (e - 1.0f) * __builtin_amdgcn_rcpf(e + 1.0f);
}
#define DOT2(w, h, acc) __builtin_amdgcn_fdot2((w), (h), (acc), false)

// One wave per (dir, batch): 1024 blocks x 64 threads = 1 wave/SIMD, zero
// barriers, no MFMA, no AGPRs. Lane j owns unit j. Whh held as f16 k-pairs
// (96 VGPRs; h-side hi/lo split preserves ~fp32-grade accuracy), Wih as f16
// pairs (24 VGPRs). h_bar broadcast via two u16 LDS arrays (hi, lo) ->
// 16 broadcast ds_read_b128/step on the LDS pipe, overlapped with the
// 240 v_dot2_f32_f16 on the VALU pipe. In-order DS pipe gives write->read
// ordering within the wave (no barrier).
__global__ __launch_bounds__(64, 1) void brios_main(
    const float* __restrict__ x, const float* __restrict__ dt,
    const float* __restrict__ f_Wih, const float* __restrict__ f_Whh,
    const float* __restrict__ f_bih, const float* __restrict__ f_bhh,
    const float* __restrict__ f_gamma, const float* __restrict__ f_Wout,
    const float* __restrict__ f_bout,
    const float* __restrict__ b_Wih, const float* __restrict__ b_Whh,
    const float* __restrict__ b_bih, const float* __restrict__ b_bhh,
    const float* __restrict__ b_gamma, const float* __restrict__ b_Wout,
    const float* __restrict__ b_bout,
    float* __restrict__ out)
{
    const int lane = threadIdx.x;
    const int dir  = blockIdx.x >> 9;
    const int b    = blockIdx.x & 511;

    const float* Wih  = dir ? b_Wih  : f_Wih;
    const float* Whh  = dir ? b_Whh  : f_Whh;
    const float* bih  = dir ? b_bih  : f_bih;
    const float* bhh  = dir ? b_bhh  : f_bhh;
    const float* Wout = dir ? b_Wout : f_Wout;
    float gam = dir ? b_gamma[0] : f_gamma[0];
    gam = fminf(fmaxf(gam, 1e-4f), 10.0f);
    const float bo = dir ? b_bout[0] : f_bout[0];

    // ---- weights as f16 k-pairs: lane j owns rows j, 64+j, 128+j
    unsigned whr[32], whz[32], whn[32];
#pragma unroll
    for (int p = 0; p < 32; ++p) {
        const float* r0 = Whh + (size_t)(      lane) * HH + 2 * p;
        const float* r1 = Whh + (size_t)( 64 + lane) * HH + 2 * p;
        const float* r2 = Whh + (size_t)(128 + lane) * HH + 2 * p;
        whr[p] = pk2_(r0[0], r0[1]);
        whz[p] = pk2_(r1[0], r1[1]);
        whn[p] = pk2_(r2[0], r2[1]);
    }
    unsigned wxr[8], wxz[8], wxn[8];
#pragma unroll
    for (int p = 0; p < 8; ++p) {
        const float* r0 = Wih + (size_t)(      lane) * DD + 2 * p;
        const float* r1 = Wih + (size_t)( 64 + lane) * DD + 2 * p;
        const float* r2 = Wih + (size_t)(128 + lane) * DD + 2 * p;
        wxr[p] = pk2_(r0[0], r0[1]);
        wxz[p] = pk2_(r1[0], r1[1]);
        wxn[p] = pk2_(r2[0], r2[1]);
    }
    const float br  = bih[lane]      + bhh[lane];
    const float bz  = bih[64 + lane] + bhh[64 + lane];
    const float bni = bih[128 + lane];
    const float bnh = bhh[128 + lane];
    const float wo  = Wout[lane];

    __shared__ alignas(16) unsigned short sh_hh[HH];  // hi-f16 of h_bar
    __shared__ alignas(16) unsigned short sh_hl[HH];  // lo-f16 of h_bar
    __shared__ alignas(16) unsigned sh_xh[CH][8];     // x hi-f16 pairs
    __shared__ alignas(16) unsigned sh_xl[CH][8];     // x lo-f16 pairs
    __shared__ float sh_dcy[CH + 1];
    __shared__ float sh_y[CH];

    sh_hh[lane] = 0;
    sh_hl[lane] = 0;
    float h_reg = 0.0f;      // lane j holds h[j] in fp32

    float* yd = out + (size_t)(1 + dir) * (BB * LL);

#pragma unroll 1
    for (int c = 0; c < LL / CH; ++c) {
        const int sbase = c * CH;
        const int t_low = dir ? (LL - CH - sbase) : sbase;

        // ---- stage x as f16 hi/lo pairs (1 float4/lane) + decay factors
        {
            int tq = lane >> 2, d4 = lane & 3;
            float4 v = *(const float4*)(x + ((size_t)b * LL + t_low + tq) * DD + d4 * 4);
            int sl = dir ? (CH - 1 - tq) : tq;
            uint2 hp, lp;
            hp.x = pk2_(v.x, v.y);
            hp.y = pk2_(v.z, v.w);
            lp.x = pk2_(flo_(v.x), flo_(v.y));
            lp.y = pk2_(flo_(v.z), flo_(v.w));
            *(uint2*)&sh_xh[sl][d4 * 2] = hp;
            *(uint2*)&sh_xl[sl][d4 * 2] = lp;
            if (lane < CH + 1) {
                int g = sbase + lane;
                if (g >= LL) {
                    sh_dcy[lane] = 1.0f;
                } else {
                    int t = dir ? (LL - 1 - g) : g;
                    float dv = dt[(size_t)b * LL + t];
                    dv = fminf(fmaxf(dv, 0.0f), 1e6f);
                    sh_dcy[lane] = __expf(-gam * dv);
                }
            }
        }
        // single wave: in-order DS pipe, no barrier needed

        // ---- recurrent steps
#pragma unroll 1
        for (int i = 0; i < CH; ++i) {
            // broadcast reads: h_bar hi/lo pairs (written end of prev step)
            unsigned hhu[32], hlu[32];
            const uint4* HHp = (const uint4*)sh_hh;
            const uint4* HLp = (const uint4*)sh_hl;
#pragma unroll
            for (int q = 0; q < 8; ++q) {
                *(uint4*)&hhu[q * 4] = HHp[q];
                *(uint4*)&hlu[q * 4] = HLp[q];
            }
            unsigned xhu[8], xlu[8];
            *(uint4*)&xhu[0] = *(const uint4*)&sh_xh[i][0];
            *(uint4*)&xhu[4] = *(const uint4*)&sh_xh[i][4];
            *(uint4*)&xlu[0] = *(const uint4*)&sh_xl[i][0];
            *(uint4*)&xlu[4] = *(const uint4*)&sh_xl[i][4];
            float dcy = sh_dcy[i];
            float hbar = dcy * h_reg;          // own-lane exact fp32 h_bar

            float rh = 0.f, rl = 0.f, zh = 0.f, zl = 0.f, nh = 0.f, nl = 0.f;
#pragma unroll
            for (int p = 0; p < 32; ++p) {
                half2_t hp = h2(hhu[p]), lp = h2(hlu[p]);
                rh = DOT2(h2(whr[p]), hp, rh);
                zh = DOT2(h2(whz[p]), hp, zh);
                nh = DOT2(h2(whn[p]), hp, nh);
                rl = DOT2(h2(whr[p]), lp, rl);
                zl = DOT2(h2(whz[p]), lp, zl);
                nl = DOT2(h2(whn[p]), lp, nl);
            }
            float gr = 0.f, gz = 0.f, gn = 0.f, qr = 0.f, qz = 0.f, qn = 0.f;
#pragma unroll
            for (int p = 0; p < 8; ++p) {
                half2_t xp = h2(xhu[p]), xq = h2(xlu[p]);
                gr = DOT2(h2(wxr[p]), xp, gr);
                gz = DOT2(h2(wxz[p]), xp, gz);
                gn = DOT2(h2(wxn[p]), xp, gn);
                qr = DOT2(h2(wxr[p]), xq, qr);
                qz = DOT2(h2(wxz[p]), xq, qz);
                qn = DOT2(h2(wxn[p]), xq, qn);
            }
            float ar  = (rh + rl) + (gr + qr) + br;
            float az  = (zh + zl) + (gz + qz) + bz;
            float anx = (gn + qn) + bni;       // i_n (x part)
            float anv = (nh + nl) + bnh;       // h_n (h part)

            float r = sigmoidf_(ar);
            float z = sigmoidf_(az);
            float n = tanhf_(anx + r * anv);
            h_reg = n + z * (hbar - n);

            // write next step's h_bar as f16 hi/lo (in-order DS pipe)
            float hb2 = sh_dcy[i + 1] * h_reg;
            _Float16 hhi = (_Float16)hb2;
            float lof = hb2 - (float)hhi;
            sh_hh[lane] = __builtin_bit_cast(unsigned short, hhi);
            sh_hl[lane] = __builtin_bit_cast(unsigned short, (_Float16)lof);

            // y via shuffle butterfly on exact fp32 h
            float v = wo * h_reg;
#pragma unroll
            for (int sft = 32; sft >= 1; sft >>= 1) v += __shfl_xor(v, sft, 64);
            sh_y[i] = v + bo;                  // uniform value
        }

        // ---- flush y coalesced
        if (lane < CH) {
            int s = sbase + lane;
            int t = dir ? (LL - 1 - s) : s;
            yd[(size_t)b * LL + t] = sh_y[lane];
        }
    }
}

__global__ __launch_bounds__(256) void brios_avg(float* __restrict__ out)
{
    int i = blockIdx.x * blockDim.x + threadIdx.x;
    const int n4 = (BB * LL) / 4;
    if (i < n4) {
        const float4* yf = (const float4*)(out + (size_t)BB * LL);
        const float4* yb = (const float4*)(out + (size_t)2 * BB * LL);
        float4 a = yf[i], b2 = yb[i];
        float4 r;
        r.x = 0.5f * (a.x + b2.x);
        r.y = 0.5f * (a.y + b2.y);
        r.z = 0.5f * (a.z + b2.z);
        r.w = 0.5f * (a.w + b2.w);
        ((float4*)out)[i] = r;
    }
}

extern "C" void kernel_launch(void* const* d_in, const int* in_sizes, int n_in,
                              void* d_out, int out_size, void* d_ws, size_t ws_size,
                              hipStream_t stream) {
    const float* x       = (const float*)d_in[0];
    const float* dt      = (const float*)d_in[1];
    const float* f_Wih   = (const float*)d_in[2];
    const float* f_Whh   = (const float*)d_in[3];
    const float* f_bih   = (const float*)d_in[4];
    const float* f_bhh   = (const float*)d_in[5];
    const float* f_gamma = (const float*)d_in[6];
    const float* f_Wout  = (const float*)d_in[7];
    const float* f_bout  = (const float*)d_in[8];
    const float* b_Wih   = (const float*)d_in[9];
    const float* b_Whh   = (const float*)d_in[10];
    const float* b_bih   = (const float*)d_in[11];
    const float* b_bhh   = (const float*)d_in[12];
    const float* b_gamma = (const float*)d_in[13];
    const float* b_Wout  = (const float*)d_in[14];
    const float* b_bout  = (const float*)d_in[15];
    float* out = (float*)d_out;

    brios_main<<<1024, 64, 0, stream>>>(x, dt,
        f_Wih, f_Whh, f_bih, f_bhh, f_gamma, f_Wout, f_bout,
        b_Wih, b_Whh, b_bih, b_bhh, b_gamma, b_Wout, b_bout, out);

    const int n4 = (BB * LL) / 4;
    brios_avg<<<(n4 + 255) / 256, 256, 0, stream>>>(out);
}

// Round 7
// 963.062 us; speedup vs baseline: 1.4780x; 1.4780x over previous
//
#include <hip/hip_runtime.h>

#define BB 512
#define LL 1024
#define DD 16
#define HH 64
#define CH 16    // timesteps per chunk

typedef _Float16 half2_t __attribute__((ext_vector_type(2)));

__device__ __forceinline__ half2_t h2(unsigned u) {
    return __builtin_bit_cast(half2_t, u);
}
__device__ __forceinline__ unsigned pk2_(float a, float b) {
    unsigned ha = (unsigned)__builtin_bit_cast(unsigned short, (_Float16)a);
    unsigned hb = (unsigned)__builtin_bit_cast(unsigned short, (_Float16)b);
    return ha | (hb << 16);
}
__device__ __forceinline__ float flo_(float a) {   // a - f16(a)
    return a - (float)((_Float16)a);
}
__device__ __forceinline__ float sigmoidf_(float x) {
    return __builtin_amdgcn_rcpf(1.0f + __expf(-x));
}
__device__ __forceinline__ float tanhf_(float x) {
    x = fminf(fmaxf(x, -15.0f), 15.0f);
    float e = __expf(2.0f * x);
    return (e - 1.0f) * __builtin_amdgcn_rcpf(e + 1.0f);
}
__device__ __forceinline__ float bcast_(float v, int k) {
    return __uint_as_float(__builtin_amdgcn_readlane(__float_as_uint(v), k));
}
#define DOT2(w, h, acc) __builtin_amdgcn_fdot2((w), (h), (acc), false)

// One wave per (dir, batch): 1024 blocks x 64 threads = 1 wave/SIMD, zero
// barriers, NO MFMA (keeps allocator away from AGPR demotion). Lane j owns
// unit j. Whh resident fp32 (192 VGPRs) -> exact recurrence matvec via
// 64 v_readlane + 192 v_fmac per step, nothing but registers on the h-chain.
// gi = Wih*x precomputed per 16-step chunk with f16 dot2 (Wih = 24 packed
// regs, x staged hi/lo in LDS); x-path quantization does not compound
// through the recurrence. Peak live set ~240 VGPR < 256.
__global__ __launch_bounds__(64, 1) void brios_main(
    const float* __restrict__ x, const float* __restrict__ dt,
    const float* __restrict__ f_Wih, const float* __restrict__ f_Whh,
    const float* __restrict__ f_bih, const float* __restrict__ f_bhh,
    const float* __restrict__ f_gamma, const float* __restrict__ f_Wout,
    const float* __restrict__ f_bout,
    const float* __restrict__ b_Wih, const float* __restrict__ b_Whh,
    const float* __restrict__ b_bih, const float* __restrict__ b_bhh,
    const float* __restrict__ b_gamma, const float* __restrict__ b_Wout,
    const float* __restrict__ b_bout,
    float* __restrict__ out)
{
    const int lane = threadIdx.x;
    const int dir  = blockIdx.x >> 9;
    const int b    = blockIdx.x & 511;

    const float* Wih  = dir ? b_Wih  : f_Wih;
    const float* Whh  = dir ? b_Whh  : f_Whh;
    const float* bih  = dir ? b_bih  : f_bih;
    const float* bhh  = dir ? b_bhh  : f_bhh;
    const float* Wout = dir ? b_Wout : f_Wout;
    float gam = dir ? b_gamma[0] : f_gamma[0];
    gam = fminf(fmaxf(gam, 1e-4f), 10.0f);
    const float bo = dir ? b_bout[0] : f_bout[0];

    // ---- Whh resident fp32: lane j holds rows j, 64+j, 128+j (192 VGPRs)
    float wr[HH], wz[HH], wn[HH];
#pragma unroll
    for (int k = 0; k < HH; ++k) {
        wr[k] = Whh[(size_t)(      lane) * HH + k];
        wz[k] = Whh[(size_t)( 64 + lane) * HH + k];
        wn[k] = Whh[(size_t)(128 + lane) * HH + k];
    }
    // ---- Wih as f16 k-pairs (24 regs)
    unsigned wxr[8], wxz[8], wxn[8];
#pragma unroll
    for (int p = 0; p < 8; ++p) {
        const float* r0 = Wih + (size_t)(      lane) * DD + 2 * p;
        const float* r1 = Wih + (size_t)( 64 + lane) * DD + 2 * p;
        const float* r2 = Wih + (size_t)(128 + lane) * DD + 2 * p;
        wxr[p] = pk2_(r0[0], r0[1]);
        wxz[p] = pk2_(r1[0], r1[1]);
        wxn[p] = pk2_(r2[0], r2[1]);
    }
    const float br  = bih[lane]      + bhh[lane];
    const float bz  = bih[64 + lane] + bhh[64 + lane];
    const float bni = bih[128 + lane];
    const float bnh = bhh[128 + lane];
    const float wo  = Wout[lane];

    __shared__ alignas(16) unsigned sh_xh[CH][8];   // x hi-f16 pairs
    __shared__ alignas(16) unsigned sh_xl[CH][8];   // x lo-f16 pairs
    __shared__ alignas(16) float sh_gi[CH][3 * HH]; // Wih*x per chunk
    __shared__ float sh_dcy[CH];
    __shared__ float sh_y[CH];

    float h_reg = 0.0f;      // lane j holds h[j], fp32 exact
    float* yd = out + (size_t)(1 + dir) * (BB * LL);

#pragma unroll 1
    for (int c = 0; c < LL / CH; ++c) {
        const int sbase = c * CH;
        const int t_low = dir ? (LL - CH - sbase) : sbase;

        // ---- stage x as f16 hi/lo pairs (1 float4/lane) + decay factors
        {
            int tq = lane >> 2, d4 = lane & 3;
            float4 v = *(const float4*)(x + ((size_t)b * LL + t_low + tq) * DD + d4 * 4);
            int sl = dir ? (CH - 1 - tq) : tq;
            uint2 hp, lp;
            hp.x = pk2_(v.x, v.y);
            hp.y = pk2_(v.z, v.w);
            lp.x = pk2_(flo_(v.x), flo_(v.y));
            lp.y = pk2_(flo_(v.z), flo_(v.w));
            *(uint2*)&sh_xh[sl][d4 * 2] = hp;
            *(uint2*)&sh_xl[sl][d4 * 2] = lp;
            if (lane < CH) {
                int t = dir ? (LL - 1 - (sbase + lane)) : (sbase + lane);
                float dv = dt[(size_t)b * LL + t];
                dv = fminf(fmaxf(dv, 0.0f), 1e6f);
                sh_dcy[lane] = __expf(-gam * dv);
            }
        }
        // single wave: in-order DS pipe + compiler waitcnts, no barrier

        // ---- gi = Wih * x for the chunk (f16 dot2, fp32 accumulate)
#pragma unroll 1
        for (int i = 0; i < CH; ++i) {
            unsigned xh[8], xl[8];
            *(uint4*)&xh[0] = *(const uint4*)&sh_xh[i][0];
            *(uint4*)&xh[4] = *(const uint4*)&sh_xh[i][4];
            *(uint4*)&xl[0] = *(const uint4*)&sh_xl[i][0];
            *(uint4*)&xl[4] = *(const uint4*)&sh_xl[i][4];
            float gr = 0.f, gz = 0.f, gn = 0.f;
#pragma unroll
            for (int p = 0; p < 8; ++p) {
                half2_t hp = h2(xh[p]);
                gr = DOT2(h2(wxr[p]), hp, gr);
                gz = DOT2(h2(wxz[p]), hp, gz);
                gn = DOT2(h2(wxn[p]), hp, gn);
            }
#pragma unroll
            for (int p = 0; p < 8; ++p) {
                half2_t lp = h2(xl[p]);
                gr = DOT2(h2(wxr[p]), lp, gr);
                gz = DOT2(h2(wxz[p]), lp, gz);
                gn = DOT2(h2(wxn[p]), lp, gn);
            }
            sh_gi[i][lane]       = gr;
            sh_gi[i][64 + lane]  = gz;
            sh_gi[i][128 + lane] = gn;
        }

        // ---- recurrent steps: registers + readlane only on the h-chain
#pragma unroll 1
        for (int i = 0; i < CH; ++i) {
            float gir = sh_gi[i][lane];
            float giz = sh_gi[i][64 + lane];
            float gin = sh_gi[i][128 + lane];
            float hbar = sh_dcy[i] * h_reg;

            float a0 = 0.f, a1 = 0.f, z0 = 0.f, z1 = 0.f, n0 = 0.f, n1 = 0.f;
#pragma unroll
            for (int k = 0; k < HH; k += 2) {
                float hk0 = bcast_(hbar, k);
                float hk1 = bcast_(hbar, k + 1);
                a0 = fmaf(wr[k], hk0, a0);
                z0 = fmaf(wz[k], hk0, z0);
                n0 = fmaf(wn[k], hk0, n0);
                a1 = fmaf(wr[k + 1], hk1, a1);
                z1 = fmaf(wz[k + 1], hk1, z1);
                n1 = fmaf(wn[k + 1], hk1, n1);
            }
            float r = sigmoidf_((a0 + a1) + gir + br);
            float z = sigmoidf_((z0 + z1) + giz + bz);
            float n = tanhf_((gin + bni) + r * ((n0 + n1) + bnh));
            h_reg = n + z * (hbar - n);

            float v = wo * h_reg;
#pragma unroll
            for (int sft = 32; sft >= 1; sft >>= 1) v += __shfl_xor(v, sft, 64);
            if (lane == 0) sh_y[i] = v + bo;
        }

        // ---- flush y coalesced
        if (lane < CH) {
            int s = sbase + lane;
            int t = dir ? (LL - 1 - s) : s;
            yd[(size_t)b * LL + t] = sh_y[lane];
        }
    }
}

__global__ __launch_bounds__(256) void brios_avg(float* __restrict__ out)
{
    int i = blockIdx.x * blockDim.x + threadIdx.x;
    const int n4 = (BB * LL) / 4;
    if (i < n4) {
        const float4* yf = (const float4*)(out + (size_t)BB * LL);
        const float4* yb = (const float4*)(out + (size_t)2 * BB * LL);
        float4 a = yf[i], b2 = yb[i];
        float4 r;
        r.x = 0.5f * (a.x + b2.x);
        r.y = 0.5f * (a.y + b2.y);
        r.z = 0.5f * (a.z + b2.z);
        r.w = 0.5f * (a.w + b2.w);
        ((float4*)out)[i] = r;
    }
}

extern "C" void kernel_launch(void* const* d_in, const int* in_sizes, int n_in,
                              void* d_out, int out_size, void* d_ws, size_t ws_size,
                              hipStream_t stream) {
    const float* x       = (const float*)d_in[0];
    const float* dt      = (const float*)d_in[1];
    const float* f_Wih   = (const float*)d_in[2];
    const float* f_Whh   = (const float*)d_in[3];
    const float* f_bih   = (const float*)d_in[4];
    const float* f_bhh   = (const float*)d_in[5];
    const float* f_gamma = (const float*)d_in[6];
    const float* f_Wout  = (const float*)d_in[7];
    const float* f_bout  = (const float*)d_in[8];
    const float* b_Wih   = (const float*)d_in[9];
    const float* b_Whh   = (const float*)d_in[10];
    const float* b_bih   = (const float*)d_in[11];
    const float* b_bhh   = (const float*)d_in[12];
    const float* b_gamma = (const float*)d_in[13];
    const float* b_Wout  = (const float*)d_in[14];
    const float* b_bout  = (const float*)d_in[15];
    float* out = (float*)d_out;

    brios_main<<<1024, 64, 0, stream>>>(x, dt,
        f_Wih, f_Whh, f_bih, f_bhh, f_gamma, f_Wout, f_bout,
        b_Wih, b_Whh, b_bih, b_bhh, b_gamma, b_Wout, b_bout, out);

    const int n4 = (BB * LL) / 4;
    brios_avg<<<(n4 + 255) / 256, 256, 0, stream>>>(out);
}

// Round 8
// 766.899 us; speedup vs baseline: 1.8560x; 1.2558x over previous
//
#include <hip/hip_runtime.h>

#define BB 512
#define LL 1024
#define DD 16
#define HH 64
#define CH 16    // timesteps per chunk
#define YP 68    // sh_yp row stride (floats), padded: 2-way bank alias only

typedef _Float16 half2_t __attribute__((ext_vector_type(2)));

__device__ __forceinline__ half2_t h2(unsigned u) {
    return __builtin_bit_cast(half2_t, u);
}
__device__ __forceinline__ unsigned pk2_(float a, float b) {
    unsigned ha = (unsigned)__builtin_bit_cast(unsigned short, (_Float16)a);
    unsigned hb = (unsigned)__builtin_bit_cast(unsigned short, (_Float16)b);
    return ha | (hb << 16);
}
__device__ __forceinline__ float flo_(float a) {   // a - f16(a)
    return a - (float)((_Float16)a);
}
__device__ __forceinline__ float sigmoidf_(float x) {
    return __builtin_amdgcn_rcpf(1.0f + __expf(-x));
}
__device__ __forceinline__ float tanhf_(float x) {
    x = fminf(fmaxf(x, -15.0f), 15.0f);
    float e = __expf(2.0f * x);
    return (e - 1.0f) * __builtin_amdgcn_rcpf(e + 1.0f);
}
__device__ __forceinline__ float bcast_(float v, int k) {
    return __uint_as_float(__builtin_amdgcn_readlane(__float_as_uint(v), k));
}
#define DOT2(w, h, acc) __builtin_amdgcn_fdot2((w), (h), (acc), false)

// One wave per (dir, batch): 1024 blocks x 64 threads, zero barriers, no MFMA.
// KEY: __launch_bounds__(64, 2) caps the unified register budget at 256/wave,
// which removes the allocator's AGPR headroom -> the 192-float Whh array must
// stay in arch VGPRs (R2/R5/R7 all showed AGPR demotion + per-use copies at
// budget 512). Step chain: 64 v_readlane + 192 v_fmac + gates, registers only.
// y products go to LDS per step (off-chain) and are reduced per chunk.
__global__ __launch_bounds__(64, 2) void brios_main(
    const float* __restrict__ x, const float* __restrict__ dt,
    const float* __restrict__ f_Wih, const float* __restrict__ f_Whh,
    const float* __restrict__ f_bih, const float* __restrict__ f_bhh,
    const float* __restrict__ f_gamma, const float* __restrict__ f_Wout,
    const float* __restrict__ f_bout,
    const float* __restrict__ b_Wih, const float* __restrict__ b_Whh,
    const float* __restrict__ b_bih, const float* __restrict__ b_bhh,
    const float* __restrict__ b_gamma, const float* __restrict__ b_Wout,
    const float* __restrict__ b_bout,
    float* __restrict__ out)
{
    const int lane = threadIdx.x;
    const int dir  = blockIdx.x >> 9;
    const int b    = blockIdx.x & 511;

    const float* Wih  = dir ? b_Wih  : f_Wih;
    const float* Whh  = dir ? b_Whh  : f_Whh;
    const float* bih  = dir ? b_bih  : f_bih;
    const float* bhh  = dir ? b_bhh  : f_bhh;
    const float* Wout = dir ? b_Wout : f_Wout;
    float gam = dir ? b_gamma[0] : f_gamma[0];
    gam = fminf(fmaxf(gam, 1e-4f), 10.0f);
    const float bo = dir ? b_bout[0] : f_bout[0];

    // ---- Wih first (small): f16 k-pairs, 24 regs
    unsigned wxr[8], wxz[8], wxn[8];
#pragma unroll
    for (int p = 0; p < 8; ++p) {
        const float* r0 = Wih + (size_t)(      lane) * DD + 2 * p;
        const float* r1 = Wih + (size_t)( 64 + lane) * DD + 2 * p;
        const float* r2 = Wih + (size_t)(128 + lane) * DD + 2 * p;
        wxr[p] = pk2_(r0[0], r0[1]);
        wxz[p] = pk2_(r1[0], r1[1]);
        wxn[p] = pk2_(r2[0], r2[1]);
    }
    // ---- Whh resident fp32: lane j holds rows j, 64+j, 128+j (192 VGPRs)
    float wr[HH], wz[HH], wn[HH];
#pragma unroll
    for (int k = 0; k < HH; ++k)
        wr[k] = Whh[(size_t)lane * HH + k];
#pragma unroll
    for (int k = 0; k < HH; ++k)
        wz[k] = Whh[(size_t)(64 + lane) * HH + k];
#pragma unroll
    for (int k = 0; k < HH; ++k)
        wn[k] = Whh[(size_t)(128 + lane) * HH + k];

    const float br  = bih[lane]      + bhh[lane];
    const float bz  = bih[64 + lane] + bhh[64 + lane];
    const float bni = bih[128 + lane];
    const float bnh = bhh[128 + lane];
    const float wo  = Wout[lane];

    __shared__ alignas(16) unsigned sh_xh[CH][8];   // x hi-f16 pairs
    __shared__ alignas(16) unsigned sh_xl[CH][8];   // x lo-f16 pairs
    __shared__ alignas(16) float sh_gi[CH][3 * HH]; // Wih*x per chunk
    __shared__ alignas(16) float sh_yp[CH][YP];     // per-lane y products
    __shared__ float sh_dcy[CH];

    float h_reg = 0.0f;      // lane j holds h[j], fp32 exact
    float* yd = out + (size_t)(1 + dir) * (BB * LL);

#pragma unroll 1
    for (int c = 0; c < LL / CH; ++c) {
        const int sbase = c * CH;
        const int t_low = dir ? (LL - CH - sbase) : sbase;

        // ---- stage x as f16 hi/lo pairs (1 float4/lane) + decay factors
        {
            int tq = lane >> 2, d4 = lane & 3;
            float4 v = *(const float4*)(x + ((size_t)b * LL + t_low + tq) * DD + d4 * 4);
            int sl = dir ? (CH - 1 - tq) : tq;
            uint2 hp, lp;
            hp.x = pk2_(v.x, v.y);
            hp.y = pk2_(v.z, v.w);
            lp.x = pk2_(flo_(v.x), flo_(v.y));
            lp.y = pk2_(flo_(v.z), flo_(v.w));
            *(uint2*)&sh_xh[sl][d4 * 2] = hp;
            *(uint2*)&sh_xl[sl][d4 * 2] = lp;
            if (lane < CH) {
                int t = dir ? (LL - 1 - (sbase + lane)) : (sbase + lane);
                float dv = dt[(size_t)b * LL + t];
                dv = fminf(fmaxf(dv, 0.0f), 1e6f);
                sh_dcy[lane] = __expf(-gam * dv);
            }
        }
        // single wave: in-order DS pipe + compiler waitcnts, no barrier

        // ---- gi = Wih * x for the chunk (f16 dot2, fp32 accumulate)
#pragma unroll 1
        for (int i = 0; i < CH; ++i) {
            unsigned xh[8], xl[8];
            *(uint4*)&xh[0] = *(const uint4*)&sh_xh[i][0];
            *(uint4*)&xh[4] = *(const uint4*)&sh_xh[i][4];
            *(uint4*)&xl[0] = *(const uint4*)&sh_xl[i][0];
            *(uint4*)&xl[4] = *(const uint4*)&sh_xl[i][4];
            float gr = 0.f, gz = 0.f, gn = 0.f;
#pragma unroll
            for (int p = 0; p < 8; ++p) {
                half2_t hp = h2(xh[p]);
                gr = DOT2(h2(wxr[p]), hp, gr);
                gz = DOT2(h2(wxz[p]), hp, gz);
                gn = DOT2(h2(wxn[p]), hp, gn);
            }
#pragma unroll
            for (int p = 0; p < 8; ++p) {
                half2_t lp = h2(xl[p]);
                gr = DOT2(h2(wxr[p]), lp, gr);
                gz = DOT2(h2(wxz[p]), lp, gz);
                gn = DOT2(h2(wxn[p]), lp, gn);
            }
            sh_gi[i][lane]       = gr;
            sh_gi[i][64 + lane]  = gz;
            sh_gi[i][128 + lane] = gn;
        }

        // ---- recurrent steps: registers + readlane only on the h-chain
#pragma unroll 1
        for (int i = 0; i < CH; ++i) {
            float gir = sh_gi[i][lane];
            float giz = sh_gi[i][64 + lane];
            float gin = sh_gi[i][128 + lane];
            float dcy = sh_dcy[i];

            float a0 = 0.f, a1 = 0.f, z0 = 0.f, z1 = 0.f, n0 = 0.f, n1 = 0.f;
#pragma unroll
            for (int k = 0; k < HH; k += 2) {
                float hk0 = bcast_(h_reg, k);        // broadcast raw h
                float hk1 = bcast_(h_reg, k + 1);
                a0 = fmaf(wr[k], hk0, a0);
                z0 = fmaf(wz[k], hk0, z0);
                n0 = fmaf(wn[k], hk0, n0);
                a1 = fmaf(wr[k + 1], hk1, a1);
                z1 = fmaf(wz[k + 1], hk1, z1);
                n1 = fmaf(wn[k + 1], hk1, n1);
            }
            float hbar = dcy * h_reg;                // own-lane update
            float r = sigmoidf_(fmaf(dcy, a0 + a1, gir + br));
            float z = sigmoidf_(fmaf(dcy, z0 + z1, giz + bz));
            float n = tanhf_((gin + bni) + r * fmaf(dcy, n0 + n1, bnh));
            h_reg = n + z * (hbar - n);

            sh_yp[i][lane] = wo * h_reg;             // off-chain y product
        }

        // ---- y: lanes 0..15 reduce their step's 64 products, store coalesced
        if (lane < CH) {
            float4 s4 = {0.f, 0.f, 0.f, 0.f};
            const float* rowp = &sh_yp[lane][0];
#pragma unroll
            for (int q = 0; q < 16; ++q) {
                float4 v = *(const float4*)(rowp + q * 4);
                s4.x += v.x; s4.y += v.y; s4.z += v.z; s4.w += v.w;
            }
            float s = (s4.x + s4.y) + (s4.z + s4.w);
            int si = sbase + lane;
            int t = dir ? (LL - 1 - si) : si;
            yd[(size_t)b * LL + t] = s + bo;
        }
    }
}

__global__ __launch_bounds__(256) void brios_avg(float* __restrict__ out)
{
    int i = blockIdx.x * blockDim.x + threadIdx.x;
    const int n4 = (BB * LL) / 4;
    if (i < n4) {
        const float4* yf = (const float4*)(out + (size_t)BB * LL);
        const float4* yb = (const float4*)(out + (size_t)2 * BB * LL);
        float4 a = yf[i], b2 = yb[i];
        float4 r;
        r.x = 0.5f * (a.x + b2.x);
        r.y = 0.5f * (a.y + b2.y);
        r.z = 0.5f * (a.z + b2.z);
        r.w = 0.5f * (a.w + b2.w);
        ((float4*)out)[i] = r;
    }
}

extern "C" void kernel_launch(void* const* d_in, const int* in_sizes, int n_in,
                              void* d_out, int out_size, void* d_ws, size_t ws_size,
                              hipStream_t stream) {
    const float* x       = (const float*)d_in[0];
    const float* dt      = (const float*)d_in[1];
    const float* f_Wih   = (const float*)d_in[2];
    const float* f_Whh   = (const float*)d_in[3];
    const float* f_bih   = (const float*)d_in[4];
    const float* f_bhh   = (const float*)d_in[5];
    const float* f_gamma = (const float*)d_in[6];
    const float* f_Wout  = (const float*)d_in[7];
    const float* f_bout  = (const float*)d_in[8];
    const float* b_Wih   = (const float*)d_in[9];
    const float* b_Whh   = (const float*)d_in[10];
    const float* b_bih   = (const float*)d_in[11];
    const float* b_bhh   = (const float*)d_in[12];
    const float* b_gamma = (const float*)d_in[13];
    const float* b_Wout  = (const float*)d_in[14];
    const float* b_bout  = (const float*)d_in[15];
    float* out = (float*)d_out;

    brios_main<<<1024, 64, 0, stream>>>(x, dt,
        f_Wih, f_Whh, f_bih, f_bhh, f_gamma, f_Wout, f_bout,
        b_Wih, b_Whh, b_bih, b_bhh, b_gamma, b_Wout, b_bout, out);

    const int n4 = (BB * LL) / 4;
    brios_avg<<<(n4 + 255) / 256, 256, 0, stream>>>(out);
}

// Round 9
// 764.794 us; speedup vs baseline: 1.8612x; 1.0028x over previous
//
#include <hip/hip_runtime.h>

#define BB 512
#define LL 1024
#define DD 16
#define HH 64
#define CH 16    // timesteps per chunk
#define YP 68    // sh_yp row stride (floats), padded: 2-way bank alias only

typedef _Float16 half2_t __attribute__((ext_vector_type(2)));

__device__ __forceinline__ half2_t h2(unsigned u) {
    return __builtin_bit_cast(half2_t, u);
}
__device__ __forceinline__ unsigned pk2_(float a, float b) {
    unsigned ha = (unsigned)__builtin_bit_cast(unsigned short, (_Float16)a);
    unsigned hb = (unsigned)__builtin_bit_cast(unsigned short, (_Float16)b);
    return ha | (hb << 16);
}
__device__ __forceinline__ float flo_(float a) {   // a - f16(a)
    return a - (float)((_Float16)a);
}
__device__ __forceinline__ float sigmoidf_(float x) {
    return __builtin_amdgcn_rcpf(1.0f + __expf(-x));
}
__device__ __forceinline__ float tanhf_(float x) {
    x = fminf(fmaxf(x, -15.0f), 15.0f);
    float e = __expf(2.0f * x);
    return (e - 1.0f) * __builtin_amdgcn_rcpf(e + 1.0f);
}
__device__ __forceinline__ float bcast_(float v, int k) {
    return __uint_as_float(__builtin_amdgcn_readlane(__float_as_uint(v), k));
}
#define DOT2(w, h, acc) __builtin_amdgcn_fdot2((w), (h), (acc), false)

// Ban the AGPR file: empty asm clobbering ALL AGPRs. Executed every chunk,
// so no long-lived value can be parked in an AGPR (R2/R5/R7/R8 all showed
// the allocator demoting the weight arrays to AGPRs + per-use v_accvgpr
// copies, ~660 wasted cyc/step). Zero dynamic instructions.
#define AGPR_CLOBBER() asm volatile("" ::: \
    "a0","a1","a2","a3","a4","a5","a6","a7","a8","a9","a10","a11","a12","a13","a14","a15", \
    "a16","a17","a18","a19","a20","a21","a22","a23","a24","a25","a26","a27","a28","a29","a30","a31", \
    "a32","a33","a34","a35","a36","a37","a38","a39","a40","a41","a42","a43","a44","a45","a46","a47", \
    "a48","a49","a50","a51","a52","a53","a54","a55","a56","a57","a58","a59","a60","a61","a62","a63", \
    "a64","a65","a66","a67","a68","a69","a70","a71","a72","a73","a74","a75","a76","a77","a78","a79", \
    "a80","a81","a82","a83","a84","a85","a86","a87","a88","a89","a90","a91","a92","a93","a94","a95", \
    "a96","a97","a98","a99","a100","a101","a102","a103","a104","a105","a106","a107","a108","a109","a110","a111", \
    "a112","a113","a114","a115","a116","a117","a118","a119","a120","a121","a122","a123","a124","a125","a126","a127", \
    "a128","a129","a130","a131","a132","a133","a134","a135","a136","a137","a138","a139","a140","a141","a142","a143", \
    "a144","a145","a146","a147","a148","a149","a150","a151","a152","a153","a154","a155","a156","a157","a158","a159", \
    "a160","a161","a162","a163","a164","a165","a166","a167","a168","a169","a170","a171","a172","a173","a174","a175", \
    "a176","a177","a178","a179","a180","a181","a182","a183","a184","a185","a186","a187","a188","a189","a190","a191", \
    "a192","a193","a194","a195","a196","a197","a198","a199","a200","a201","a202","a203","a204","a205","a206","a207", \
    "a208","a209","a210","a211","a212","a213","a214","a215","a216","a217","a218","a219","a220","a221","a222","a223", \
    "a224","a225","a226","a227","a228","a229","a230","a231","a232","a233","a234","a235","a236","a237","a238","a239", \
    "a240","a241","a242","a243","a244","a245","a246","a247","a248","a249","a250","a251","a252","a253","a254","a255")

// One wave per (dir, batch): 1024 blocks x 64 threads, zero barriers, no MFMA.
// Whh resident fp32 (192 arch VGPRs, AGPR file banned). Step chain:
// 64 v_readlane + 192 v_fmac + gates, registers only. gi = Wih*x per chunk
// via f16 dot2 (24 packed regs). y products to LDS per step (off-chain),
// reduced per chunk by lanes 0..15.
__global__ __launch_bounds__(64, 1) void brios_main(
    const float* __restrict__ x, const float* __restrict__ dt,
    const float* __restrict__ f_Wih, const float* __restrict__ f_Whh,
    const float* __restrict__ f_bih, const float* __restrict__ f_bhh,
    const float* __restrict__ f_gamma, const float* __restrict__ f_Wout,
    const float* __restrict__ f_bout,
    const float* __restrict__ b_Wih, const float* __restrict__ b_Whh,
    const float* __restrict__ b_bih, const float* __restrict__ b_bhh,
    const float* __restrict__ b_gamma, const float* __restrict__ b_Wout,
    const float* __restrict__ b_bout,
    float* __restrict__ out)
{
    const int lane = threadIdx.x;
    const int dir  = blockIdx.x >> 9;
    const int b    = blockIdx.x & 511;

    const float* Wih  = dir ? b_Wih  : f_Wih;
    const float* Whh  = dir ? b_Whh  : f_Whh;
    const float* bih  = dir ? b_bih  : f_bih;
    const float* bhh  = dir ? b_bhh  : f_bhh;
    const float* Wout = dir ? b_Wout : f_Wout;
    float gam = dir ? b_gamma[0] : f_gamma[0];
    gam = fminf(fmaxf(gam, 1e-4f), 10.0f);
    const float bo = dir ? b_bout[0] : f_bout[0];

    // ---- Wih first (small): f16 k-pairs, 24 regs
    unsigned wxr[8], wxz[8], wxn[8];
#pragma unroll
    for (int p = 0; p < 8; ++p) {
        const float* r0 = Wih + (size_t)(      lane) * DD + 2 * p;
        const float* r1 = Wih + (size_t)( 64 + lane) * DD + 2 * p;
        const float* r2 = Wih + (size_t)(128 + lane) * DD + 2 * p;
        wxr[p] = pk2_(r0[0], r0[1]);
        wxz[p] = pk2_(r1[0], r1[1]);
        wxn[p] = pk2_(r2[0], r2[1]);
    }
    // ---- Whh resident fp32: lane j holds rows j, 64+j, 128+j (192 VGPRs)
    float wr[HH], wz[HH], wn[HH];
#pragma unroll
    for (int k = 0; k < HH; ++k)
        wr[k] = Whh[(size_t)lane * HH + k];
#pragma unroll
    for (int k = 0; k < HH; ++k)
        wz[k] = Whh[(size_t)(64 + lane) * HH + k];
#pragma unroll
    for (int k = 0; k < HH; ++k)
        wn[k] = Whh[(size_t)(128 + lane) * HH + k];

    const float br  = bih[lane]      + bhh[lane];
    const float bz  = bih[64 + lane] + bhh[64 + lane];
    const float bni = bih[128 + lane];
    const float bnh = bhh[128 + lane];
    const float wo  = Wout[lane];

    __shared__ alignas(16) unsigned sh_xh[CH][8];   // x hi-f16 pairs
    __shared__ alignas(16) unsigned sh_xl[CH][8];   // x lo-f16 pairs
    __shared__ alignas(16) float sh_gi[CH][3 * HH]; // Wih*x per chunk
    __shared__ alignas(16) float sh_yp[CH][YP];     // per-lane y products
    __shared__ float sh_dcy[CH];

    float h_reg = 0.0f;      // lane j holds h[j], fp32 exact
    float* yd = out + (size_t)(1 + dir) * (BB * LL);

#pragma unroll 1
    for (int c = 0; c < LL / CH; ++c) {
        AGPR_CLOBBER();      // no value may live in an AGPR across a chunk

        const int sbase = c * CH;
        const int t_low = dir ? (LL - CH - sbase) : sbase;

        // ---- stage x as f16 hi/lo pairs (1 float4/lane) + decay factors
        {
            int tq = lane >> 2, d4 = lane & 3;
            float4 v = *(const float4*)(x + ((size_t)b * LL + t_low + tq) * DD + d4 * 4);
            int sl = dir ? (CH - 1 - tq) : tq;
            uint2 hp, lp;
            hp.x = pk2_(v.x, v.y);
            hp.y = pk2_(v.z, v.w);
            lp.x = pk2_(flo_(v.x), flo_(v.y));
            lp.y = pk2_(flo_(v.z), flo_(v.w));
            *(uint2*)&sh_xh[sl][d4 * 2] = hp;
            *(uint2*)&sh_xl[sl][d4 * 2] = lp;
            if (lane < CH) {
                int t = dir ? (LL - 1 - (sbase + lane)) : (sbase + lane);
                float dv = dt[(size_t)b * LL + t];
                dv = fminf(fmaxf(dv, 0.0f), 1e6f);
                sh_dcy[lane] = __expf(-gam * dv);
            }
        }
        // single wave: in-order DS pipe + compiler waitcnts, no barrier

        // ---- gi = Wih * x for the chunk (f16 dot2, fp32 accumulate)
#pragma unroll 1
        for (int i = 0; i < CH; ++i) {
            unsigned xh[8], xl[8];
            *(uint4*)&xh[0] = *(const uint4*)&sh_xh[i][0];
            *(uint4*)&xh[4] = *(const uint4*)&sh_xh[i][4];
            *(uint4*)&xl[0] = *(const uint4*)&sh_xl[i][0];
            *(uint4*)&xl[4] = *(const uint4*)&sh_xl[i][4];
            float gr = 0.f, gz = 0.f, gn = 0.f;
#pragma unroll
            for (int p = 0; p < 8; ++p) {
                half2_t hp = h2(xh[p]);
                gr = DOT2(h2(wxr[p]), hp, gr);
                gz = DOT2(h2(wxz[p]), hp, gz);
                gn = DOT2(h2(wxn[p]), hp, gn);
            }
#pragma unroll
            for (int p = 0; p < 8; ++p) {
                half2_t lp = h2(xl[p]);
                gr = DOT2(h2(wxr[p]), lp, gr);
                gz = DOT2(h2(wxz[p]), lp, gz);
                gn = DOT2(h2(wxn[p]), lp, gn);
            }
            sh_gi[i][lane]       = gr;
            sh_gi[i][64 + lane]  = gz;
            sh_gi[i][128 + lane] = gn;
        }

        // ---- recurrent steps: registers + readlane only on the h-chain
#pragma unroll 1
        for (int i = 0; i < CH; ++i) {
            float gir = sh_gi[i][lane];
            float giz = sh_gi[i][64 + lane];
            float gin = sh_gi[i][128 + lane];
            float dcy = sh_dcy[i];

            float a0 = 0.f, a1 = 0.f, z0 = 0.f, z1 = 0.f, n0 = 0.f, n1 = 0.f;
#pragma unroll
            for (int k = 0; k < HH; k += 2) {
                float hk0 = bcast_(h_reg, k);        // broadcast raw h
                float hk1 = bcast_(h_reg, k + 1);
                a0 = fmaf(wr[k], hk0, a0);
                z0 = fmaf(wz[k], hk0, z0);
                n0 = fmaf(wn[k], hk0, n0);
                a1 = fmaf(wr[k + 1], hk1, a1);
                z1 = fmaf(wz[k + 1], hk1, z1);
                n1 = fmaf(wn[k + 1], hk1, n1);
            }
            float hbar = dcy * h_reg;                // own-lane update
            float r = sigmoidf_(fmaf(dcy, a0 + a1, gir + br));
            float z = sigmoidf_(fmaf(dcy, z0 + z1, giz + bz));
            float n = tanhf_((gin + bni) + r * fmaf(dcy, n0 + n1, bnh));
            h_reg = n + z * (hbar - n);

            sh_yp[i][lane] = wo * h_reg;             // off-chain y product
        }

        // ---- y: lanes 0..15 reduce their step's 64 products, store coalesced
        if (lane < CH) {
            float4 s4 = {0.f, 0.f, 0.f, 0.f};
            const float* rowp = &sh_yp[lane][0];
#pragma unroll
            for (int q = 0; q < 16; ++q) {
                float4 v = *(const float4*)(rowp + q * 4);
                s4.x += v.x; s4.y += v.y; s4.z += v.z; s4.w += v.w;
            }
            float s = (s4.x + s4.y) + (s4.z + s4.w);
            int si = sbase + lane;
            int t = dir ? (LL - 1 - si) : si;
            yd[(size_t)b * LL + t] = s + bo;
        }
    }
}

__global__ __launch_bounds__(256) void brios_avg(float* __restrict__ out)
{
    int i = blockIdx.x * blockDim.x + threadIdx.x;
    const int n4 = (BB * LL) / 4;
    if (i < n4) {
        const float4* yf = (const float4*)(out + (size_t)BB * LL);
        const float4* yb = (const float4*)(out + (size_t)2 * BB * LL);
        float4 a = yf[i], b2 = yb[i];
        float4 r;
        r.x = 0.5f * (a.x + b2.x);
        r.y = 0.5f * (a.y + b2.y);
        r.z = 0.5f * (a.z + b2.z);
        r.w = 0.5f * (a.w + b2.w);
        ((float4*)out)[i] = r;
    }
}

extern "C" void kernel_launch(void* const* d_in, const int* in_sizes, int n_in,
                              void* d_out, int out_size, void* d_ws, size_t ws_size,
                              hipStream_t stream) {
    const float* x       = (const float*)d_in[0];
    const float* dt      = (const float*)d_in[1];
    const float* f_Wih   = (const float*)d_in[2];
    const float* f_Whh   = (const float*)d_in[3];
    const float* f_bih   = (const float*)d_in[4];
    const float* f_bhh   = (const float*)d_in[5];
    const float* f_gamma = (const float*)d_in[6];
    const float* f_Wout  = (const float*)d_in[7];
    const float* f_bout  = (const float*)d_in[8];
    const float* b_Wih   = (const float*)d_in[9];
    const float* b_Whh   = (const float*)d_in[10];
    const float* b_bih   = (const float*)d_in[11];
    const float* b_bhh   = (const float*)d_in[12];
    const float* b_gamma = (const float*)d_in[13];
    const float* b_Wout  = (const float*)d_in[14];
    const float* b_bout  = (const float*)d_in[15];
    float* out = (float*)d_out;

    brios_main<<<1024, 64, 0, stream>>>(x, dt,
        f_Wih, f_Whh, f_bih, f_bhh, f_gamma, f_Wout, f_bout,
        b_Wih, b_Whh, b_bih, b_bhh, b_gamma, b_Wout, b_bout, out);

    const int n4 = (BB * LL) / 4;
    brios_avg<<<(n4 + 255) / 256, 256, 0, stream>>>(out);
}

// Round 11
// 683.814 us; speedup vs baseline: 2.0816x; 1.1184x over previous
//
#include <hip/hip_runtime.h>

#define BB 512
#define LL 1024
#define DD 16
#define HH 64
#define CH 16    // timesteps per chunk
#define YP 68    // sh_yp row stride (floats), padded: 2-way bank alias only

typedef _Float16 half2_t __attribute__((ext_vector_type(2)));

__device__ __forceinline__ half2_t h2(unsigned u) {
    return __builtin_bit_cast(half2_t, u);
}
__device__ __forceinline__ unsigned pk2_(float a, float b) {
    unsigned ha = (unsigned)__builtin_bit_cast(unsigned short, (_Float16)a);
    unsigned hb = (unsigned)__builtin_bit_cast(unsigned short, (_Float16)b);
    return ha | (hb << 16);
}
__device__ __forceinline__ float flo_(float a) {   // a - f16(a)
    return a - (float)((_Float16)a);
}
__device__ __forceinline__ float sigmoidf_(float x) {
    return __builtin_amdgcn_rcpf(1.0f + __expf(-x));
}
__device__ __forceinline__ float tanhf_(float x) {
    x = fminf(fmaxf(x, -15.0f), 15.0f);
    float e = __expf(2.0f * x);
    return (e - 1.0f) * __builtin_amdgcn_rcpf(e + 1.0f);
}
#define DOT2(w, h, acc) __builtin_amdgcn_fdot2((w), (h), (acc), false)

// Ban the AGPR file (see R9): keeps all long-lived arrays in arch VGPRs.
#define AGPR_CLOBBER() asm volatile("" ::: \
    "a0","a1","a2","a3","a4","a5","a6","a7","a8","a9","a10","a11","a12","a13","a14","a15", \
    "a16","a17","a18","a19","a20","a21","a22","a23","a24","a25","a26","a27","a28","a29","a30","a31", \
    "a32","a33","a34","a35","a36","a37","a38","a39","a40","a41","a42","a43","a44","a45","a46","a47", \
    "a48","a49","a50","a51","a52","a53","a54","a55","a56","a57","a58","a59","a60","a61","a62","a63", \
    "a64","a65","a66","a67","a68","a69","a70","a71","a72","a73","a74","a75","a76","a77","a78","a79", \
    "a80","a81","a82","a83","a84","a85","a86","a87","a88","a89","a90","a91","a92","a93","a94","a95", \
    "a96","a97","a98","a99","a100","a101","a102","a103","a104","a105","a106","a107","a108","a109","a110","a111", \
    "a112","a113","a114","a115","a116","a117","a118","a119","a120","a121","a122","a123","a124","a125","a126","a127", \
    "a128","a129","a130","a131","a132","a133","a134","a135","a136","a137","a138","a139","a140","a141","a142","a143", \
    "a144","a145","a146","a147","a148","a149","a150","a151","a152","a153","a154","a155","a156","a157","a158","a159", \
    "a160","a161","a162","a163","a164","a165","a166","a167","a168","a169","a170","a171","a172","a173","a174","a175", \
    "a176","a177","a178","a179","a180","a181","a182","a183","a184","a185","a186","a187","a188","a189","a190","a191", \
    "a192","a193","a194","a195","a196","a197","a198","a199","a200","a201","a202","a203","a204","a205","a206","a207", \
    "a208","a209","a210","a211","a212","a213","a214","a215","a216","a217","a218","a219","a220","a221","a222","a223", \
    "a224","a225","a226","a227","a228","a229","a230","a231","a232","a233","a234","a235","a236","a237","a238","a239", \
    "a240","a241","a242","a243","a244","a245","a246","a247","a248","a249","a250","a251","a252","a253","a254","a255")

// One wave per (dir, batch): 1024 blocks x 64 threads, zero barriers, no MFMA.
// Recurrent matvec in PACKED f16: Whh as f16 k-pairs (96 VGPRs), h_bar pairs
// packed once per step via shfl_xor+cvt_pkrtz, broadcast via 32 v_readlane of
// packed SGPRs feeding 96 v_dot2_f32_f16 -> 128 matvec insts/step (vs 256
// scalar-fp32 in R9). |h|<=1 structurally; contractive recurrence keeps the
// f16-h quantization bounded (~few e-3 at y). gi = Wih*x per chunk (f16 dot2),
// y products off-chain to LDS, reduced per chunk by lanes 0..15.
__global__ __launch_bounds__(64, 1) void brios_main(
    const float* __restrict__ x, const float* __restrict__ dt,
    const float* __restrict__ f_Wih, const float* __restrict__ f_Whh,
    const float* __restrict__ f_bih, const float* __restrict__ f_bhh,
    const float* __restrict__ f_gamma, const float* __restrict__ f_Wout,
    const float* __restrict__ f_bout,
    const float* __restrict__ b_Wih, const float* __restrict__ b_Whh,
    const float* __restrict__ b_bih, const float* __restrict__ b_bhh,
    const float* __restrict__ b_gamma, const float* __restrict__ b_Wout,
    const float* __restrict__ b_bout,
    float* __restrict__ out)
{
    const int lane = threadIdx.x;
    const int dir  = blockIdx.x >> 9;
    const int b    = blockIdx.x & 511;

    const float* Wih  = dir ? b_Wih  : f_Wih;
    const float* Whh  = dir ? b_Whh  : f_Whh;
    const float* bih  = dir ? b_bih  : f_bih;
    const float* bhh  = dir ? b_bhh  : f_bhh;
    const float* Wout = dir ? b_Wout : f_Wout;
    float gam = dir ? b_gamma[0] : f_gamma[0];
    gam = fminf(fmaxf(gam, 1e-4f), 10.0f);
    const float bo = dir ? b_bout[0] : f_bout[0];

    // ---- Wih: f16 k-pairs, 24 regs
    unsigned wxr[8], wxz[8], wxn[8];
#pragma unroll
    for (int p = 0; p < 8; ++p) {
        const float* r0 = Wih + (size_t)(      lane) * DD + 2 * p;
        const float* r1 = Wih + (size_t)( 64 + lane) * DD + 2 * p;
        const float* r2 = Wih + (size_t)(128 + lane) * DD + 2 * p;
        wxr[p] = pk2_(r0[0], r0[1]);
        wxz[p] = pk2_(r1[0], r1[1]);
        wxn[p] = pk2_(r2[0], r2[1]);
    }
    // ---- Whh: f16 k-pairs, lane j owns rows j, 64+j, 128+j (96 VGPRs)
    unsigned whr[32], whz[32], whn[32];
#pragma unroll
    for (int p = 0; p < 32; ++p) {
        const float* r0 = Whh + (size_t)(      lane) * HH + 2 * p;
        const float* r1 = Whh + (size_t)( 64 + lane) * HH + 2 * p;
        const float* r2 = Whh + (size_t)(128 + lane) * HH + 2 * p;
        whr[p] = pk2_(r0[0], r0[1]);
        whz[p] = pk2_(r1[0], r1[1]);
        whn[p] = pk2_(r2[0], r2[1]);
    }
    const float br  = bih[lane]      + bhh[lane];
    const float bz  = bih[64 + lane] + bhh[64 + lane];
    const float bni = bih[128 + lane];
    const float bnh = bhh[128 + lane];
    const float wo  = Wout[lane];

    __shared__ alignas(16) unsigned sh_xh[CH][8];   // x hi-f16 pairs
    __shared__ alignas(16) unsigned sh_xl[CH][8];   // x lo-f16 pairs
    __shared__ alignas(16) float sh_gi[CH][3 * HH]; // Wih*x per chunk
    __shared__ alignas(16) float sh_yp[CH][YP];     // per-lane y products
    __shared__ float sh_dcy[CH];

    float h_reg = 0.0f;      // lane j holds h[j], fp32
    float* yd = out + (size_t)(1 + dir) * (BB * LL);

#pragma unroll 1
    for (int c = 0; c < LL / CH; ++c) {
        AGPR_CLOBBER();      // no value may live in an AGPR across a chunk

        const int sbase = c * CH;
        const int t_low = dir ? (LL - CH - sbase) : sbase;

        // ---- stage x as f16 hi/lo pairs (1 float4/lane) + decay factors
        {
            int tq = lane >> 2, d4 = lane & 3;
            float4 v = *(const float4*)(x + ((size_t)b * LL + t_low + tq) * DD + d4 * 4);
            int sl = dir ? (CH - 1 - tq) : tq;
            uint2 hp, lp;
            hp.x = pk2_(v.x, v.y);
            hp.y = pk2_(v.z, v.w);
            lp.x = pk2_(flo_(v.x), flo_(v.y));
            lp.y = pk2_(flo_(v.z), flo_(v.w));
            *(uint2*)&sh_xh[sl][d4 * 2] = hp;
            *(uint2*)&sh_xl[sl][d4 * 2] = lp;
            if (lane < CH) {
                int t = dir ? (LL - 1 - (sbase + lane)) : (sbase + lane);
                float dv = dt[(size_t)b * LL + t];
                dv = fminf(fmaxf(dv, 0.0f), 1e6f);
                sh_dcy[lane] = __expf(-gam * dv);
            }
        }
        // single wave: in-order DS pipe + compiler waitcnts, no barrier

        // ---- gi = Wih * x for the chunk (f16 dot2, fp32 accumulate)
#pragma unroll 1
        for (int i = 0; i < CH; ++i) {
            unsigned xh[8], xl[8];
            *(uint4*)&xh[0] = *(const uint4*)&sh_xh[i][0];
            *(uint4*)&xh[4] = *(const uint4*)&sh_xh[i][4];
            *(uint4*)&xl[0] = *(const uint4*)&sh_xl[i][0];
            *(uint4*)&xl[4] = *(const uint4*)&sh_xl[i][4];
            float gr = 0.f, gz = 0.f, gn = 0.f;
#pragma unroll
            for (int p = 0; p < 8; ++p) {
                half2_t hp = h2(xh[p]);
                gr = DOT2(h2(wxr[p]), hp, gr);
                gz = DOT2(h2(wxz[p]), hp, gz);
                gn = DOT2(h2(wxn[p]), hp, gn);
            }
#pragma unroll
            for (int p = 0; p < 8; ++p) {
                half2_t lp = h2(xl[p]);
                gr = DOT2(h2(wxr[p]), lp, gr);
                gz = DOT2(h2(wxz[p]), lp, gz);
                gn = DOT2(h2(wxn[p]), lp, gn);
            }
            sh_gi[i][lane]       = gr;
            sh_gi[i][64 + lane]  = gz;
            sh_gi[i][128 + lane] = gn;
        }

        // ---- recurrent steps: packed-pair broadcast, registers only
#pragma unroll 1
        for (int i = 0; i < CH; ++i) {
            float gir = sh_gi[i][lane];
            float giz = sh_gi[i][64 + lane];
            float gin = sh_gi[i][128 + lane];
            float dcy = sh_dcy[i];

            float hbar = dcy * h_reg;                 // decay applied up front
            float hprt = __shfl_xor(hbar, 1, 64);     // partner element
            unsigned hpku = __builtin_bit_cast(unsigned,
                                __builtin_amdgcn_cvt_pkrtz(hbar, hprt));
            // even lane 2m now holds packed (hbar[2m], hbar[2m+1])

            float ra = 0.f, za = 0.f, na = 0.f;
#pragma unroll
            for (int p = 0; p < 32; ++p) {
                unsigned hs = (unsigned)__builtin_amdgcn_readlane((int)hpku, 2 * p);
                half2_t hh = h2(hs);
                ra = DOT2(h2(whr[p]), hh, ra);
                za = DOT2(h2(whz[p]), hh, za);
                na = DOT2(h2(whn[p]), hh, na);
            }
            float r = sigmoidf_(ra + gir + br);
            float z = sigmoidf_(za + giz + bz);
            float n = tanhf_((gin + bni) + r * (na + bnh));
            h_reg = n + z * (hbar - n);

            sh_yp[i][lane] = wo * h_reg;              // off-chain y product
        }

        // ---- y: lanes 0..15 reduce their step's 64 products, store coalesced
        if (lane < CH) {
            float4 s4 = {0.f, 0.f, 0.f, 0.f};
            const float* rowp = &sh_yp[lane][0];
#pragma unroll
            for (int q = 0; q < 16; ++q) {
                float4 v = *(const float4*)(rowp + q * 4);
                s4.x += v.x; s4.y += v.y; s4.z += v.z; s4.w += v.w;
            }
            float s = (s4.x + s4.y) + (s4.z + s4.w);
            int si = sbase + lane;
            int t = dir ? (LL - 1 - si) : si;
            yd[(size_t)b * LL + t] = s + bo;
        }
    }
}

__global__ __launch_bounds__(256) void brios_avg(float* __restrict__ out)
{
    int i = blockIdx.x * blockDim.x + threadIdx.x;
    const int n4 = (BB * LL) / 4;
    if (i < n4) {
        const float4* yf = (const float4*)(out + (size_t)BB * LL);
        const float4* yb = (const float4*)(out + (size_t)2 * BB * LL);
        float4 a = yf[i], b2 = yb[i];
        float4 r;
        r.x = 0.5f * (a.x + b2.x);
        r.y = 0.5f * (a.y + b2.y);
        r.z = 0.5f * (a.z + b2.z);
        r.w = 0.5f * (a.w + b2.w);
        ((float4*)out)[i] = r;
    }
}

extern "C" void kernel_launch(void* const* d_in, const int* in_sizes, int n_in,
                              void* d_out, int out_size, void* d_ws, size_t ws_size,
                              hipStream_t stream) {
    const float* x       = (const float*)d_in[0];
    const float* dt      = (const float*)d_in[1];
    const float* f_Wih   = (const float*)d_in[2];
    const float* f_Whh   = (const float*)d_in[3];
    const float* f_bih   = (const float*)d_in[4];
    const float* f_bhh   = (const float*)d_in[5];
    const float* f_gamma = (const float*)d_in[6];
    const float* f_Wout  = (const float*)d_in[7];
    const float* f_bout  = (const float*)d_in[8];
    const float* b_Wih   = (const float*)d_in[9];
    const float* b_Whh   = (const float*)d_in[10];
    const float* b_bih   = (const float*)d_in[11];
    const float* b_bhh   = (const float*)d_in[12];
    const float* b_gamma = (const float*)d_in[13];
    const float* b_Wout  = (const float*)d_in[14];
    const float* b_bout  = (const float*)d_in[15];
    float* out = (float*)d_out;

    brios_main<<<1024, 64, 0, stream>>>(x, dt,
        f_Wih, f_Whh, f_bih, f_bhh, f_gamma, f_Wout, f_bout,
        b_Wih, b_Whh, b_bih, b_bhh, b_gamma, b_Wout, b_bout, out);

    const int n4 = (BB * LL) / 4;
    brios_avg<<<(n4 + 255) / 256, 256, 0, stream>>>(out);
}

// Round 12
// 586.102 us; speedup vs baseline: 2.4286x; 1.1667x over previous
//
#include <hip/hip_runtime.h>

#define BB 512
#define LL 1024
#define DD 16
#define HH 64
#define CH 16    // timesteps per chunk
#define YP 68    // sh_yp row stride (floats), padded: 2-way bank alias only

typedef _Float16 half2_t __attribute__((ext_vector_type(2)));

__device__ __forceinline__ half2_t h2(unsigned u) {
    return __builtin_bit_cast(half2_t, u);
}
__device__ __forceinline__ unsigned pk2_(float a, float b) {
    unsigned ha = (unsigned)__builtin_bit_cast(unsigned short, (_Float16)a);
    unsigned hb = (unsigned)__builtin_bit_cast(unsigned short, (_Float16)b);
    return ha | (hb << 16);
}
__device__ __forceinline__ float flo_(float a) {   // a - f16(a)
    return a - (float)((_Float16)a);
}
__device__ __forceinline__ float sigmoidf_(float x) {
    return __builtin_amdgcn_rcpf(1.0f + __expf(-x));
}
__device__ __forceinline__ float tanhf_(float x) {
    x = fminf(fmaxf(x, -15.0f), 15.0f);
    float e = __expf(2.0f * x);
    return (e - 1.0f) * __builtin_amdgcn_rcpf(e + 1.0f);
}
#define DOT2(w, h, acc) __builtin_amdgcn_fdot2((w), (h), (acc), false)

// Ban the AGPR file (see R9): keeps all long-lived arrays in arch VGPRs.
#define AGPR_CLOBBER() asm volatile("" ::: \
    "a0","a1","a2","a3","a4","a5","a6","a7","a8","a9","a10","a11","a12","a13","a14","a15", \
    "a16","a17","a18","a19","a20","a21","a22","a23","a24","a25","a26","a27","a28","a29","a30","a31", \
    "a32","a33","a34","a35","a36","a37","a38","a39","a40","a41","a42","a43","a44","a45","a46","a47", \
    "a48","a49","a50","a51","a52","a53","a54","a55","a56","a57","a58","a59","a60","a61","a62","a63", \
    "a64","a65","a66","a67","a68","a69","a70","a71","a72","a73","a74","a75","a76","a77","a78","a79", \
    "a80","a81","a82","a83","a84","a85","a86","a87","a88","a89","a90","a91","a92","a93","a94","a95", \
    "a96","a97","a98","a99","a100","a101","a102","a103","a104","a105","a106","a107","a108","a109","a110","a111", \
    "a112","a113","a114","a115","a116","a117","a118","a119","a120","a121","a122","a123","a124","a125","a126","a127", \
    "a128","a129","a130","a131","a132","a133","a134","a135","a136","a137","a138","a139","a140","a141","a142","a143", \
    "a144","a145","a146","a147","a148","a149","a150","a151","a152","a153","a154","a155","a156","a157","a158","a159", \
    "a160","a161","a162","a163","a164","a165","a166","a167","a168","a169","a170","a171","a172","a173","a174","a175", \
    "a176","a177","a178","a179","a180","a181","a182","a183","a184","a185","a186","a187","a188","a189","a190","a191", \
    "a192","a193","a194","a195","a196","a197","a198","a199","a200","a201","a202","a203","a204","a205","a206","a207", \
    "a208","a209","a210","a211","a212","a213","a214","a215","a216","a217","a218","a219","a220","a221","a222","a223", \
    "a224","a225","a226","a227","a228","a229","a230","a231","a232","a233","a234","a235","a236","a237","a238","a239", \
    "a240","a241","a242","a243","a244","a245","a246","a247","a248","a249","a250","a251","a252","a253","a254","a255")

// One wave per (dir, batch): 1024 blocks x 64 threads, zero barriers, no MFMA.
// R12: software-pipelined step loop. The x-path dot2s are folded into the
// gate accumulators (h-independent -> free ILP under the hbar/readlane
// chain), and step i+1's x/decay registers are prefetched during step i
// (ping-pong, manual 2-unroll) so LDS latency hides behind ~400 cyc of
// dot2 issue. No sh_gi round-trip. Whh f16 k-pairs (96 VGPRs), 32 packed
// readlane + 144 dot2 per step, all registers on the h-chain.
__global__ __launch_bounds__(64, 1) void brios_main(
    const float* __restrict__ x, const float* __restrict__ dt,
    const float* __restrict__ f_Wih, const float* __restrict__ f_Whh,
    const float* __restrict__ f_bih, const float* __restrict__ f_bhh,
    const float* __restrict__ f_gamma, const float* __restrict__ f_Wout,
    const float* __restrict__ f_bout,
    const float* __restrict__ b_Wih, const float* __restrict__ b_Whh,
    const float* __restrict__ b_bih, const float* __restrict__ b_bhh,
    const float* __restrict__ b_gamma, const float* __restrict__ b_Wout,
    const float* __restrict__ b_bout,
    float* __restrict__ out)
{
    const int lane = threadIdx.x;
    const int dir  = blockIdx.x >> 9;
    const int b    = blockIdx.x & 511;

    const float* Wih  = dir ? b_Wih  : f_Wih;
    const float* Whh  = dir ? b_Whh  : f_Whh;
    const float* bih  = dir ? b_bih  : f_bih;
    const float* bhh  = dir ? b_bhh  : f_bhh;
    const float* Wout = dir ? b_Wout : f_Wout;
    float gam = dir ? b_gamma[0] : f_gamma[0];
    gam = fminf(fmaxf(gam, 1e-4f), 10.0f);
    const float bo = dir ? b_bout[0] : f_bout[0];

    // ---- Wih: f16 k-pairs, 24 regs
    unsigned wxr[8], wxz[8], wxn[8];
#pragma unroll
    for (int p = 0; p < 8; ++p) {
        const float* r0 = Wih + (size_t)(      lane) * DD + 2 * p;
        const float* r1 = Wih + (size_t)( 64 + lane) * DD + 2 * p;
        const float* r2 = Wih + (size_t)(128 + lane) * DD + 2 * p;
        wxr[p] = pk2_(r0[0], r0[1]);
        wxz[p] = pk2_(r1[0], r1[1]);
        wxn[p] = pk2_(r2[0], r2[1]);
    }
    // ---- Whh: f16 k-pairs, lane j owns rows j, 64+j, 128+j (96 VGPRs)
    unsigned whr[32], whz[32], whn[32];
#pragma unroll
    for (int p = 0; p < 32; ++p) {
        const float* r0 = Whh + (size_t)(      lane) * HH + 2 * p;
        const float* r1 = Whh + (size_t)( 64 + lane) * HH + 2 * p;
        const float* r2 = Whh + (size_t)(128 + lane) * HH + 2 * p;
        whr[p] = pk2_(r0[0], r0[1]);
        whz[p] = pk2_(r1[0], r1[1]);
        whn[p] = pk2_(r2[0], r2[1]);
    }
    const float br  = bih[lane]      + bhh[lane];
    const float bz  = bih[64 + lane] + bhh[64 + lane];
    const float bni = bih[128 + lane];
    const float bnh = bhh[128 + lane];
    const float wo  = Wout[lane];

    __shared__ alignas(16) unsigned sh_xh[CH][8];   // x hi-f16 pairs
    __shared__ alignas(16) unsigned sh_xl[CH][8];   // x lo-f16 pairs
    __shared__ alignas(16) float sh_yp[CH][YP];     // per-lane y products
    __shared__ float sh_dcy[CH];

    float h_reg = 0.0f;      // lane j holds h[j], fp32
    float* yd = out + (size_t)(1 + dir) * (BB * LL);

    // one GRU step; consumes (xh,xl,dcyc) regs, prefetches step `inx` into
    // (pxh,pxl,pdcy) right away so the DS latency hides under the dot2 block
    auto step = [&](int i, int inx,
                    unsigned* xh, unsigned* xl, float dcyc,
                    unsigned* pxh, unsigned* pxl, float* pdcy)
                    __attribute__((always_inline)) {
        *(uint4*)&pxh[0] = *(const uint4*)&sh_xh[inx][0];
        *(uint4*)&pxh[4] = *(const uint4*)&sh_xh[inx][4];
        *(uint4*)&pxl[0] = *(const uint4*)&sh_xl[inx][0];
        *(uint4*)&pxl[4] = *(const uint4*)&sh_xl[inx][4];
        *pdcy = sh_dcy[inx];

        float hbar = dcyc * h_reg;
        float hprt = __shfl_xor(hbar, 1, 64);
        unsigned hpku = __builtin_bit_cast(unsigned,
                            __builtin_amdgcn_cvt_pkrtz(hbar, hprt));
        // even lane 2m holds packed (hbar[2m], hbar[2m+1])

        float ra = br, za = bz, gn = bni, na = 0.f;
        // x-path (h-independent -> fills the readlane-chain latency)
#pragma unroll
        for (int p = 0; p < 8; ++p) {
            half2_t hp = h2(xh[p]);
            ra = DOT2(h2(wxr[p]), hp, ra);
            za = DOT2(h2(wxz[p]), hp, za);
            gn = DOT2(h2(wxn[p]), hp, gn);
        }
#pragma unroll
        for (int p = 0; p < 8; ++p) {
            half2_t lp = h2(xl[p]);
            ra = DOT2(h2(wxr[p]), lp, ra);
            za = DOT2(h2(wxz[p]), lp, za);
            gn = DOT2(h2(wxn[p]), lp, gn);
        }
        // h-path
#pragma unroll
        for (int p = 0; p < 32; ++p) {
            unsigned hs = (unsigned)__builtin_amdgcn_readlane((int)hpku, 2 * p);
            half2_t hh = h2(hs);
            ra = DOT2(h2(whr[p]), hh, ra);
            za = DOT2(h2(whz[p]), hh, za);
            na = DOT2(h2(whn[p]), hh, na);
        }
        float r = sigmoidf_(ra);
        float z = sigmoidf_(za);
        float n = tanhf_(gn + r * (na + bnh));
        h_reg = n + z * (hbar - n);

        sh_yp[i][lane] = wo * h_reg;     // off-chain y product
    };

#pragma unroll 1
    for (int c = 0; c < LL / CH; ++c) {
        AGPR_CLOBBER();      // no value may live in an AGPR across a chunk

        const int sbase = c * CH;
        const int t_low = dir ? (LL - CH - sbase) : sbase;

        // ---- stage x as f16 hi/lo pairs (1 float4/lane) + decay factors
        {
            int tq = lane >> 2, d4 = lane & 3;
            float4 v = *(const float4*)(x + ((size_t)b * LL + t_low + tq) * DD + d4 * 4);
            int sl = dir ? (CH - 1 - tq) : tq;
            uint2 hp, lp;
            hp.x = pk2_(v.x, v.y);
            hp.y = pk2_(v.z, v.w);
            lp.x = pk2_(flo_(v.x), flo_(v.y));
            lp.y = pk2_(flo_(v.z), flo_(v.w));
            *(uint2*)&sh_xh[sl][d4 * 2] = hp;
            *(uint2*)&sh_xl[sl][d4 * 2] = lp;
            if (lane < CH) {
                int t = dir ? (LL - 1 - (sbase + lane)) : (sbase + lane);
                float dv = dt[(size_t)b * LL + t];
                dv = fminf(fmaxf(dv, 0.0f), 1e6f);
                sh_dcy[lane] = __expf(-gam * dv);
            }
        }
        // single wave: in-order DS pipe + compiler waitcnts, no barrier

        // ---- preload step 0
        unsigned xAh[8], xAl[8], xBh[8], xBl[8];
        float dcyA, dcyB;
        *(uint4*)&xAh[0] = *(const uint4*)&sh_xh[0][0];
        *(uint4*)&xAh[4] = *(const uint4*)&sh_xh[0][4];
        *(uint4*)&xAl[0] = *(const uint4*)&sh_xl[0][0];
        *(uint4*)&xAl[4] = *(const uint4*)&sh_xl[0][4];
        dcyA = sh_dcy[0];

        // ---- recurrent steps, ping-pong prefetch (manual 2-unroll)
#pragma unroll 1
        for (int i = 0; i < CH; i += 2) {
            step(i,     i + 1,                        xAh, xAl, dcyA, xBh, xBl, &dcyB);
            step(i + 1, (i + 2 < CH) ? i + 2 : i + 1, xBh, xBl, dcyB, xAh, xAl, &dcyA);
        }

        // ---- y: lanes 0..15 reduce their step's 64 products, store coalesced
        if (lane < CH) {
            float4 s4 = {0.f, 0.f, 0.f, 0.f};
            const float* rowp = &sh_yp[lane][0];
#pragma unroll
            for (int q = 0; q < 16; ++q) {
                float4 v = *(const float4*)(rowp + q * 4);
                s4.x += v.x; s4.y += v.y; s4.z += v.z; s4.w += v.w;
            }
            float s = (s4.x + s4.y) + (s4.z + s4.w);
            int si = sbase + lane;
            int t = dir ? (LL - 1 - si) : si;
            yd[(size_t)b * LL + t] = s + bo;
        }
    }
}

__global__ __launch_bounds__(256) void brios_avg(float* __restrict__ out)
{
    int i = blockIdx.x * blockDim.x + threadIdx.x;
    const int n4 = (BB * LL) / 4;
    if (i < n4) {
        const float4* yf = (const float4*)(out + (size_t)BB * LL);
        const float4* yb = (const float4*)(out + (size_t)2 * BB * LL);
        float4 a = yf[i], b2 = yb[i];
        float4 r;
        r.x = 0.5f * (a.x + b2.x);
        r.y = 0.5f * (a.y + b2.y);
        r.z = 0.5f * (a.z + b2.z);
        r.w = 0.5f * (a.w + b2.w);
        ((float4*)out)[i] = r;
    }
}

extern "C" void kernel_launch(void* const* d_in, const int* in_sizes, int n_in,
                              void* d_out, int out_size, void* d_ws, size_t ws_size,
                              hipStream_t stream) {
    const float* x       = (const float*)d_in[0];
    const float* dt      = (const float*)d_in[1];
    const float* f_Wih   = (const float*)d_in[2];
    const float* f_Whh   = (const float*)d_in[3];
    const float* f_bih   = (const float*)d_in[4];
    const float* f_bhh   = (const float*)d_in[5];
    const float* f_gamma = (const float*)d_in[6];
    const float* f_Wout  = (const float*)d_in[7];
    const float* f_bout  = (const float*)d_in[8];
    const float* b_Wih   = (const float*)d_in[9];
    const float* b_Whh   = (const float*)d_in[10];
    const float* b_bih   = (const float*)d_in[11];
    const float* b_bhh   = (const float*)d_in[12];
    const float* b_gamma = (const float*)d_in[13];
    const float* b_Wout  = (const float*)d_in[14];
    const float* b_bout  = (const float*)d_in[15];
    float* out = (float*)d_out;

    brios_main<<<1024, 64, 0, stream>>>(x, dt,
        f_Wih, f_Whh, f_bih, f_bhh, f_gamma, f_Wout, f_bout,
        b_Wih, b_Whh, b_bih, b_bhh, b_gamma, b_Wout, b_bout, out);

    const int n4 = (BB * LL) / 4;
    brios_avg<<<(n4 + 255) / 256, 256, 0, stream>>>(out);
}